// Round 5
// baseline (963.001 us; speedup 1.0000x reference)
//
#include <hip/hip_runtime.h>
#include <hip/hip_bf16.h>

using s8 = __attribute__((ext_vector_type(8))) short;
using f4 = __attribute__((ext_vector_type(4))) float;

__device__ __forceinline__ unsigned short f2b(float f) {
    union { float f; unsigned u; } v; v.f = f;
    unsigned r = v.u + 0x7fffu + ((v.u >> 16) & 1u);
    return (unsigned short)(r >> 16);
}
__device__ __forceinline__ float softplus_f(float x) {
    return fmaxf(x, 0.f) + __logf(1.f + __expf(-fabsf(x)));
}
__device__ __forceinline__ float sigmoid_f(float x) {
    return 1.f / (1.f + __expf(-x));
}

// ---------------------------------------------------------------------------
// Tiled transpose + f32->bf16: dst[n][k] = src[k][n].  dst ld = ldst.
// ---------------------------------------------------------------------------
__global__ __launch_bounds__(256) void transpose_w(const float* __restrict__ src,
                                                   unsigned short* __restrict__ dst,
                                                   int K, int N, int ldst) {
    __shared__ float tile[32][33];
    const int n0 = blockIdx.x * 32, k0 = blockIdx.y * 32;
    const int tx = threadIdx.x, ty = threadIdx.y;
#pragma unroll
    for (int r = 0; r < 4; r++) {
        int k = k0 + ty + r * 8, n = n0 + tx;
        tile[ty + r * 8][tx] = (k < K && n < N) ? src[(size_t)k * N + n] : 0.f;
    }
    __syncthreads();
#pragma unroll
    for (int r = 0; r < 4; r++) {
        int n = n0 + ty + r * 8, k = k0 + tx;
        if (n < N && k < K) dst[(size_t)n * ldst + k] = f2b(tile[tx][ty + r * 8]);
    }
}

// ---------------------------------------------------------------------------
// WcatT[n][k] (bf16, ld 5776): k<5705 -> Wref[k + 64*(k/163)][n];
//                              k>=5705 -> sum_t Wref[t*227+163+(k-5705)][n]
// ---------------------------------------------------------------------------
__global__ __launch_bounds__(256) void wcat_t(const float* __restrict__ Wref,
                                              unsigned short* __restrict__ dst) {
    __shared__ float tile[32][33];
    const int n0 = blockIdx.x * 32, k0 = blockIdx.y * 32;
    const int tx = threadIdx.x, ty = threadIdx.y;
#pragma unroll
    for (int r = 0; r < 4; r++) {
        int k = k0 + ty + r * 8, n = n0 + tx;
        float v = 0.f;
        if (k < 5769 && n < 227) {
            if (k < 5705) {
                int wrow = k + 64 * (k / 163);
                v = Wref[(size_t)wrow * 227 + n];
            } else {
                int j2 = k - 5705;
                for (int t = 0; t < 35; t++)
                    v += Wref[(size_t)(t * 227 + 163 + j2) * 227 + n];
            }
        }
        tile[ty + r * 8][tx] = v;
    }
    __syncthreads();
#pragma unroll
    for (int r = 0; r < 4; r++) {
        int n = n0 + ty + r * 8, k = k0 + tx;
        if (n < 227 && k < 5769) dst[(size_t)n * 5776 + k] = f2b(tile[tx][ty + r * 8]);
    }
}

// ---------------------------------------------------------------------------
// Prefill: fin[4096*228]=0; flat[4096*228]=fb3[col]; ctx[4096*64]=cb3[col]
// ---------------------------------------------------------------------------
__global__ __launch_bounds__(256) void prefill_k(float* __restrict__ fin,
                                                 float* __restrict__ flat,
                                                 float* __restrict__ ctx,
                                                 const float* __restrict__ fb3,
                                                 const float* __restrict__ cb3) {
    const int S1 = 4096 * 228, S3 = 4096 * 64;
    int id = blockIdx.x * 256 + threadIdx.x;
    if (id < S1) {
        fin[id] = 0.f;
        int col = id % 228;
        flat[id] = (col < 227) ? fb3[col] : 0.f;
    } else {
        int j = id - S1;
        if (j < S3) ctx[j] = cb3[j & 63];
    }
}

// ---------------------------------------------------------------------------
// MFMA GEMM: C[M,N] (+)= act(A[M,K] @ WT^T + bias)
// WT bf16 [N][K] (ld ldwt). Tile BM x 128, BK=32.
// BM=128: 4 waves (2x2); BM=64: 2 waves (1x2). fp32 acc via 16x16x32_bf16.
// AMODE: 0 = A fp32 (lda), 1 = A bf16/ushort (lda), 2 = concat se|pz fp32.
// ATOMIC: atomicAdd f32 partials (split-K grid.z); else bias+act+store.
// ---------------------------------------------------------------------------
template <int AMODE, int ACT, bool ATOMIC, bool OBF16, int BM>
__global__ __launch_bounds__((BM / 64) * 128) void gemm_mfma(
    const void* __restrict__ Aptr, int lda,
    const float* __restrict__ A2ptr,           // pz (concat only)
    const unsigned short* __restrict__ WT, int ldwt,
    const float* __restrict__ bias,
    void* __restrict__ Cptr, int ldc,
    int M, int N, int K, int kchunk) {
    constexpr int THREADS = (BM / 64) * 128;
    __shared__ unsigned short As[BM * 40];
    __shared__ unsigned short Bs[128 * 40];

    const int tid = threadIdx.x;
    const int m0 = blockIdx.y * BM, n0 = blockIdx.x * 128;
    const int kbeg = blockIdx.z * kchunk;
    const int kend = min(kbeg + kchunk, K);
    const int lane = tid & 63, w = tid >> 6;
    const int wm = (BM == 128) ? (w >> 1) : 0;
    const int wn = (BM == 128) ? (w & 1) : w;
    const int quad = lane >> 4, l16 = lane & 15;

    f4 acc[4][4] = {};

    for (int k0 = kbeg; k0 < kend; k0 += 32) {
        const bool full = (kend - k0) >= 32;
        // ---- stage A tile: BM rows x 32 k -> As[row][k] bf16 ----
#pragma unroll
        for (int i = 0; i < 4; i++) {
            int f = tid + i * THREADS;
            int r = f >> 3, cc = (f & 7) * 4;
            int gm = m0 + r;
            ushort4 val;
            if (AMODE == 0) {
                const float* A = (const float*)Aptr;
                if (full) {
                    float4 v = *(const float4*)(A + (size_t)gm * lda + k0 + cc);
                    val.x = f2b(v.x); val.y = f2b(v.y); val.z = f2b(v.z); val.w = f2b(v.w);
                } else {
                    float t[4];
#pragma unroll
                    for (int j = 0; j < 4; j++) {
                        int k = k0 + cc + j;
                        t[j] = (k < kend) ? A[(size_t)gm * lda + k] : 0.f;
                    }
                    val.x = f2b(t[0]); val.y = f2b(t[1]); val.z = f2b(t[2]); val.w = f2b(t[3]);
                }
            } else if (AMODE == 1) {
                const unsigned short* A = (const unsigned short*)Aptr;
                if (full) {
                    val = *(const ushort4*)(A + (size_t)gm * lda + k0 + cc);
                } else {
                    unsigned short t[4];
#pragma unroll
                    for (int j = 0; j < 4; j++) {
                        int k = k0 + cc + j;
                        t[j] = (k < kend) ? A[(size_t)gm * lda + k] : (unsigned short)0;
                    }
                    val.x = t[0]; val.y = t[1]; val.z = t[2]; val.w = t[3];
                }
            } else {
                const float* se = (const float*)Aptr;
                int kc = k0 + cc;
                if (kc + 3 < 5705 && full) {
                    // fast path: 4 coalesced se loads, no per-element branch
                    const float* sp = se + (size_t)gm * 5705 + kc;
                    val.x = f2b(sp[0]); val.y = f2b(sp[1]);
                    val.z = f2b(sp[2]); val.w = f2b(sp[3]);
                } else {
                    float t[4];
#pragma unroll
                    for (int j = 0; j < 4; j++) {
                        int k = kc + j;
                        float v = 0.f;
                        if (k < kend) {
                            v = (k < 5705) ? se[(size_t)gm * 5705 + k]
                                           : A2ptr[(size_t)gm * 64 + (k - 5705)];
                        }
                        t[j] = v;
                    }
                    val.x = f2b(t[0]); val.y = f2b(t[1]); val.z = f2b(t[2]); val.w = f2b(t[3]);
                }
            }
            *(ushort4*)&As[r * 40 + cc] = val;
        }
        // ---- stage W tile: WT rows n0..n0+127 (bf16) ----
#pragma unroll
        for (int i = 0; i < 1024 / THREADS; i++) {
            int f = tid + i * THREADS;
            int r = f >> 3, cc = (f & 7) * 4;
            int gn = n0 + r;
            ushort4 val;
            if (gn < N) {
                if (full) {
                    val = *(const ushort4*)(WT + (size_t)gn * ldwt + k0 + cc);
                } else {
                    unsigned short t[4];
#pragma unroll
                    for (int j = 0; j < 4; j++) {
                        int k = k0 + cc + j;
                        t[j] = (k < kend) ? WT[(size_t)gn * ldwt + k] : (unsigned short)0;
                    }
                    val.x = t[0]; val.y = t[1]; val.z = t[2]; val.w = t[3];
                }
            } else {
                val.x = val.y = val.z = val.w = 0;
            }
            *(ushort4*)&Bs[r * 40 + cc] = val;
        }
        __syncthreads();
        // ---- compute: 16 MFMA ----
        s8 a[4], b[4];
#pragma unroll
        for (int mi = 0; mi < 4; mi++)
            a[mi] = *(const s8*)&As[(wm * 64 + mi * 16 + l16) * 40 + quad * 8];
#pragma unroll
        for (int ni = 0; ni < 4; ni++)
            b[ni] = *(const s8*)&Bs[(wn * 64 + ni * 16 + l16) * 40 + quad * 8];
#pragma unroll
        for (int mi = 0; mi < 4; mi++)
#pragma unroll
            for (int ni = 0; ni < 4; ni++)
                acc[mi][ni] = __builtin_amdgcn_mfma_f32_16x16x32_bf16(
                    a[mi], b[ni], acc[mi][ni], 0, 0, 0);
        __syncthreads();
    }

    // ---- epilogue: D[row=quad*4+r][col=l16] per frag ----
#pragma unroll
    for (int mi = 0; mi < 4; mi++) {
        int gmb = m0 + wm * 64 + mi * 16 + quad * 4;
#pragma unroll
        for (int ni = 0; ni < 4; ni++) {
            int gn = n0 + wn * 64 + ni * 16 + l16;
            if (gn < N) {
#pragma unroll
                for (int r = 0; r < 4; r++) {
                    float v = acc[mi][ni][r];
                    size_t off = (size_t)(gmb + r) * ldc + gn;
                    if (ATOMIC) {
                        atomicAdd((float*)Cptr + off, v);
                    } else {
                        if (bias) v += bias[gn];
                        if (ACT == 1) v = softplus_f(v);
                        if (OBF16) ((unsigned short*)Cptr)[off] = f2b(v);
                        else ((float*)Cptr)[off] = v;
                    }
                }
            }
        }
    }
}

// ---------------------------------------------------------------------------
// g-net: out[b,62+d] = sigmoid( sum_h sp(x*gW1[d,h]+gb1[d,h]) * gW2[d,h] + gb2[d] )
// ---------------------------------------------------------------------------
__global__ __launch_bounds__(256) void g_kernel(
    const float* __restrict__ flat,
    const float* __restrict__ gW1, const float* __restrict__ gb1,
    const float* __restrict__ gW2, const float* __restrict__ gb2,
    float* __restrict__ out) {
    __shared__ float w1[227], b1[227], w2[227];
    const int d = blockIdx.x;
    const int t = threadIdx.x;
    const int b = blockIdx.y * 256 + t;
    if (t < 227) {
        w1[t] = gW1[(size_t)d * 227 + t];
        b1[t] = gb1[(size_t)d * 227 + t];
        w2[t] = gW2[(size_t)d * 227 + t];
    }
    __syncthreads();
    float x = flat[(size_t)b * 228 + d];
    float acc = gb2[d];
    for (int h = 0; h < 227; h++) {
        float z = fmaf(x, w1[h], b1[h]);
        acc = fmaf(softplus_f(z), w2[h], acc);
    }
    out[(size_t)b * 415 + 62 + d] = sigmoid_f(acc);
}

// ---------------------------------------------------------------------------
__device__ __forceinline__ float lse12(const float* s) {
    float m = s[0];
#pragma unroll
    for (int j = 1; j < 12; j++) m = fmaxf(m, s[j]);
    float sum = 0.f;
#pragma unroll
    for (int j = 0; j < 12; j++) sum += __expf(s[j] - m);
    return m + __logf(sum);
}

__global__ __launch_bounds__(256) void heads_k(
    const float* __restrict__ flat, const float* __restrict__ ctx,
    const float* __restrict__ Wl, const float* __restrict__ Wsh, const float* __restrict__ Wm,
    const float* __restrict__ cWl, const float* __restrict__ cWsh, const float* __restrict__ cWm,
    float* __restrict__ out) {
    __shared__ float fl[227];
    __shared__ float cx[64];
    __shared__ float sraw[12], craw[12];
    __shared__ float lsf, lsc;
    const int b = blockIdx.x;
    const int t = threadIdx.x;
    if (t < 227) fl[t] = flat[(size_t)b * 228 + t];
    if (t < 64) cx[t] = ctx[(size_t)b * 64 + t];
    __syncthreads();
    float* ob = out + (size_t)b * 415;

    if (t < 25) {
        float a = 0.f;
        for (int k = 0; k < 227; k++) a = fmaf(fl[k], Wl[(size_t)k * 25 + t], a);
        ob[t] = a;
    } else if (t < 37) {
        int j = t - 25;
        float a = 0.f;
        for (int k = 0; k < 227; k++) a = fmaf(fl[k], Wsh[(size_t)k * 12 + j], a);
        sraw[j] = a;
    } else if (t < 62) {
        int j = t - 37;
        float a = 0.f;
        for (int k = 0; k < 227; k++) a = fmaf(fl[k], Wm[(size_t)k * 25 + j], a);
        ob[37 + j] = a;
    } else if (t >= 64 && t < 126) {
        int j2 = t - 64;
        if (j2 < 25) {
            float a = 0.f;
            for (int k = 0; k < 64; k++) a = fmaf(cx[k], cWl[(size_t)k * 25 + j2], a);
            ob[289 + j2] = a;
        } else if (j2 < 37) {
            int j = j2 - 25;
            float a = 0.f;
            for (int k = 0; k < 64; k++) a = fmaf(cx[k], cWsh[(size_t)k * 12 + j], a);
            craw[j] = a;
        } else {
            int j = j2 - 37;
            float a = 0.f;
            for (int k = 0; k < 64; k++) a = fmaf(cx[k], cWm[(size_t)k * 25 + j], a);
            ob[326 + j] = a;
        }
    } else if (t >= 128 && t < 192) {
        ob[351 + (t - 128)] = cx[t - 128];
    }
    __syncthreads();
    if (t == 0) lsf = lse12(sraw);
    if (t == 64) lsc = lse12(craw);
    __syncthreads();
    if (t < 12) ob[25 + t] = sraw[t] - lsf;
    else if (t >= 64 && t < 76) ob[314 + (t - 64)] = craw[t - 64] - lsc;
}

// ---------------------------------------------------------------------------
extern "C" void kernel_launch(void* const* d_in, const int* in_sizes, int n_in,
                              void* d_out, int out_size, void* d_ws, size_t ws_size,
                              hipStream_t stream) {
    const float* se    = (const float*)d_in[0];   // [4096,5705]
    const float* pz    = (const float*)d_in[1];   // [4096,64]
    const float* Wref  = (const float*)d_in[2];   // [7945,227]
    const float* fW1   = (const float*)d_in[3];
    const float* fb1   = (const float*)d_in[4];
    const float* fW2   = (const float*)d_in[5];
    const float* fb2   = (const float*)d_in[6];
    const float* fW3   = (const float*)d_in[7];
    const float* fb3   = (const float*)d_in[8];
    const float* gW1   = (const float*)d_in[9];
    const float* gb1   = (const float*)d_in[10];
    const float* gW2   = (const float*)d_in[11];
    const float* gb2   = (const float*)d_in[12];
    const float* Wland = (const float*)d_in[13];
    const float* Wshot = (const float*)d_in[14];
    const float* Wmove = (const float*)d_in[15];
    const float* cW1   = (const float*)d_in[16];
    const float* cb1   = (const float*)d_in[17];
    const float* cW2   = (const float*)d_in[18];
    const float* cb2   = (const float*)d_in[19];
    const float* cW3   = (const float*)d_in[20];
    const float* cb3   = (const float*)d_in[21];
    const float* cWl   = (const float*)d_in[22];
    const float* cWs   = (const float*)d_in[23];
    const float* cWm   = (const float*)d_in[24];
    float* out = (float*)d_out;
    const int M = 4096;

    // ---- workspace layout (~31.8 MB) ----
    char* p = (char*)d_ws;
    auto alloc = [&](size_t bytes) {
        char* r = p;
        p += (bytes + 255) & ~(size_t)255;
        return r;
    };
    unsigned short* WcatT = (unsigned short*)alloc((size_t)227 * 5776 * 2);
    unsigned short* cW1T  = (unsigned short*)alloc((size_t)1024 * 64 * 2);
    unsigned short* cW2T  = (unsigned short*)alloc((size_t)1024 * 1024 * 2);
    unsigned short* cW3T  = (unsigned short*)alloc((size_t)64 * 1024 * 2);
    unsigned short* fW1T  = (unsigned short*)alloc((size_t)1024 * 228 * 2);
    unsigned short* fW2T  = (unsigned short*)alloc((size_t)1024 * 1024 * 2);
    unsigned short* fW3T  = (unsigned short*)alloc((size_t)227 * 1024 * 2);
    unsigned short* h1    = (unsigned short*)alloc((size_t)M * 1024 * 2);
    unsigned short* h2    = (unsigned short*)alloc((size_t)M * 1024 * 2);
    float* fin  = (float*)alloc((size_t)M * 228 * 4);
    float* flat = (float*)alloc((size_t)M * 228 * 4);
    float* ctxb = (float*)alloc((size_t)M * 64 * 4);

    const dim3 tb(32, 8);
    // ---- weight prep (transpose + bf16) ----
    transpose_w<<<dim3(32, 2),  tb, 0, stream>>>(cW1, cW1T, 64, 1024, 64);
    transpose_w<<<dim3(32, 32), tb, 0, stream>>>(cW2, cW2T, 1024, 1024, 1024);
    transpose_w<<<dim3(2, 32),  tb, 0, stream>>>(cW3, cW3T, 1024, 64, 1024);
    transpose_w<<<dim3(32, 8),  tb, 0, stream>>>(fW1, fW1T, 227, 1024, 228);
    transpose_w<<<dim3(32, 32), tb, 0, stream>>>(fW2, fW2T, 1024, 1024, 1024);
    transpose_w<<<dim3(8, 32),  tb, 0, stream>>>(fW3, fW3T, 1024, 227, 1024);
    wcat_t<<<dim3(8, 181), tb, 0, stream>>>(Wref, WcatT);
    prefill_k<<<dim3((4096 * 228 + 4096 * 64 + 255) / 256), 256, 0, stream>>>(
        fin, flat, ctxb, fb3, cb3);

    // ---- context chain (BM=64 variants: 512 blocks, 2 blocks/CU) ----
    gemm_mfma<0, 1, false, true, 64><<<dim3(8, 64, 1), 128, 0, stream>>>(
        pz, 64, nullptr, cW1T, 64, cb1, h1, 1024, M, 1024, 64, 64);
    gemm_mfma<1, 1, false, true, 64><<<dim3(8, 64, 1), 128, 0, stream>>>(
        h1, 1024, nullptr, cW2T, 1024, cb2, h2, 1024, M, 1024, 1024, 1024);
    gemm_mfma<1, 0, true, false, 128><<<dim3(1, 32, 16), 256, 0, stream>>>(
        h2, 1024, nullptr, cW3T, 1024, nullptr, ctxb, 64, M, 64, 1024, 64);

    // ---- encoder: fin = [se|pz] @ Wcat (split-K=16, atomic f32) ----
    gemm_mfma<2, 0, true, false, 128><<<dim3(2, 32, 16), 256, 0, stream>>>(
        se, 5705, pz, WcatT, 5776, nullptr, fin, 228, M, 227, 5769, 384);

    // ---- f-decoder chain ----
    gemm_mfma<0, 1, false, true, 64><<<dim3(8, 64, 1), 128, 0, stream>>>(
        fin, 228, nullptr, fW1T, 228, fb1, h1, 1024, M, 1024, 227, 227);
    gemm_mfma<1, 1, false, true, 64><<<dim3(8, 64, 1), 128, 0, stream>>>(
        h1, 1024, nullptr, fW2T, 1024, fb2, h2, 1024, M, 1024, 1024, 1024);
    gemm_mfma<1, 0, true, false, 128><<<dim3(2, 32, 8), 256, 0, stream>>>(
        h2, 1024, nullptr, fW3T, 1024, nullptr, flat, 228, M, 227, 1024, 128);

    // ---- g-net + heads ----
    g_kernel<<<dim3(227, 16), 256, 0, stream>>>(flat, gW1, gb1, gW2, gb2, out);
    heads_k<<<dim3(4096), 256, 0, stream>>>(flat, ctxb, Wland, Wshot, Wmove,
                                            cWl, cWs, cWm, out);
}

// Round 6
// 883.803 us; speedup vs baseline: 1.0896x; 1.0896x over previous
//
#include <hip/hip_runtime.h>
#include <hip/hip_bf16.h>

using s8 = __attribute__((ext_vector_type(8))) short;
using f4 = __attribute__((ext_vector_type(4))) float;

__device__ __forceinline__ unsigned short f2b(float f) {
    union { float f; unsigned u; } v; v.f = f;
    unsigned r = v.u + 0x7fffu + ((v.u >> 16) & 1u);
    return (unsigned short)(r >> 16);
}
__device__ __forceinline__ float softplus_f(float x) {
    return fmaxf(x, 0.f) + __logf(1.f + __expf(-fabsf(x)));
}
__device__ __forceinline__ float sigmoid_f(float x) {
    return 1.f / (1.f + __expf(-x));
}

// ---------------------------------------------------------------------------
// Tiled transpose + f32->bf16: dst[n][k] = src[k][n].  dst ld = ldst.
// ---------------------------------------------------------------------------
__global__ __launch_bounds__(256) void transpose_w(const float* __restrict__ src,
                                                   unsigned short* __restrict__ dst,
                                                   int K, int N, int ldst) {
    __shared__ float tile[32][33];
    const int n0 = blockIdx.x * 32, k0 = blockIdx.y * 32;
    const int tx = threadIdx.x, ty = threadIdx.y;
#pragma unroll
    for (int r = 0; r < 4; r++) {
        int k = k0 + ty + r * 8, n = n0 + tx;
        tile[ty + r * 8][tx] = (k < K && n < N) ? src[(size_t)k * N + n] : 0.f;
    }
    __syncthreads();
#pragma unroll
    for (int r = 0; r < 4; r++) {
        int n = n0 + ty + r * 8, k = k0 + tx;
        if (n < N && k < K) dst[(size_t)n * ldst + k] = f2b(tile[tx][ty + r * 8]);
    }
}

// ---------------------------------------------------------------------------
// WcatT[n][k] (bf16, ld 5776): k<5705 -> Wref[k + 64*(k/163)][n];
//                              k>=5705 -> sum_t Wref[t*227+163+(k-5705)][n]
// ---------------------------------------------------------------------------
__global__ __launch_bounds__(256) void wcat_t(const float* __restrict__ Wref,
                                              unsigned short* __restrict__ dst) {
    __shared__ float tile[32][33];
    const int n0 = blockIdx.x * 32, k0 = blockIdx.y * 32;
    const int tx = threadIdx.x, ty = threadIdx.y;
#pragma unroll
    for (int r = 0; r < 4; r++) {
        int k = k0 + ty + r * 8, n = n0 + tx;
        float v = 0.f;
        if (k < 5769 && n < 227) {
            if (k < 5705) {
                int wrow = k + 64 * (k / 163);
                v = Wref[(size_t)wrow * 227 + n];
            } else {
                int j2 = k - 5705;
                for (int t = 0; t < 35; t++)
                    v += Wref[(size_t)(t * 227 + 163 + j2) * 227 + n];
            }
        }
        tile[ty + r * 8][tx] = v;
    }
    __syncthreads();
#pragma unroll
    for (int r = 0; r < 4; r++) {
        int n = n0 + ty + r * 8, k = k0 + tx;
        if (n < 227 && k < 5769) dst[(size_t)n * 5776 + k] = f2b(tile[tx][ty + r * 8]);
    }
}

// ---------------------------------------------------------------------------
// Prefill: fin[4096*228]=0; flat[4096*228]=fb3[col]; ctx[4096*64]=cb3[col]
// ---------------------------------------------------------------------------
__global__ __launch_bounds__(256) void prefill_k(float* __restrict__ fin,
                                                 float* __restrict__ flat,
                                                 float* __restrict__ ctx,
                                                 const float* __restrict__ fb3,
                                                 const float* __restrict__ cb3) {
    const int S1 = 4096 * 228, S3 = 4096 * 64;
    int id = blockIdx.x * 256 + threadIdx.x;
    if (id < S1) {
        fin[id] = 0.f;
        int col = id % 228;
        flat[id] = (col < 227) ? fb3[col] : 0.f;
    } else {
        int j = id - S1;
        if (j < S3) ctx[j] = cb3[j & 63];
    }
}

// ---------------------------------------------------------------------------
// MFMA GEMM with register-prefetch software pipeline.
// C[M,N] (+)= act(A[M,K] @ WT^T + bias); WT bf16 [N][K] (ld ldwt).
// Tile BM x 128, BK=32. BM=128: 4 waves (2x2). fp32 acc, 16x16x32_bf16.
// AMODE: 0 = A fp32 (lda), 1 = A bf16/ushort (lda), 2 = concat se|pz fp32.
// ATOMIC: atomicAdd f32 partials (split-K grid.z); else bias+act+store.
// Pipeline: global loads for iter k+1 issue right after barrier-1, so their
// latency overlaps the ds_read+MFMA phase (the r4/r5 version stalled on
// vmcnt(0) at the head of every iteration).
// ---------------------------------------------------------------------------
template <int AMODE, int ACT, bool ATOMIC, bool OBF16, int BM>
__global__ __launch_bounds__((BM / 64) * 128) void gemm_mfma(
    const void* __restrict__ Aptr, int lda,
    const float* __restrict__ A2ptr,           // pz (concat only)
    const unsigned short* __restrict__ WT, int ldwt,
    const float* __restrict__ bias,
    void* __restrict__ Cptr, int ldc,
    int M, int N, int K, int kchunk) {
    constexpr int THREADS = (BM / 64) * 128;
    constexpr int NA = (BM * 32) / (THREADS * 4);
    constexpr int NB = (128 * 32) / (THREADS * 4);
    __shared__ unsigned short As[BM * 40];
    __shared__ unsigned short Bs[128 * 40];

    const int tid = threadIdx.x;
    const int m0 = blockIdx.y * BM, n0 = blockIdx.x * 128;
    const int kbeg = blockIdx.z * kchunk;
    const int kend = min(kbeg + kchunk, K);
    const int lane = tid & 63, w = tid >> 6;
    const int wm = (BM == 128) ? (w >> 1) : 0;
    const int wn = (BM == 128) ? (w & 1) : w;
    const int quad = lane >> 4, l16 = lane & 15;

    f4 acc[4][4] = {};
    ushort4 pa[NA], pb[NB];

    auto loadA = [&](int k0) {
        const bool full = (kend - k0) >= 32;
#pragma unroll
        for (int i = 0; i < NA; i++) {
            int f = tid + i * THREADS;
            int r = f >> 3, cc = (f & 7) * 4;
            int gm = m0 + r;
            ushort4 val;
            if (AMODE == 0) {
                const float* A = (const float*)Aptr;
                if (full) {
                    float4 v = *(const float4*)(A + (size_t)gm * lda + k0 + cc);
                    val.x = f2b(v.x); val.y = f2b(v.y); val.z = f2b(v.z); val.w = f2b(v.w);
                } else {
                    float t[4];
#pragma unroll
                    for (int j = 0; j < 4; j++) {
                        int k = k0 + cc + j;
                        t[j] = (k < kend) ? A[(size_t)gm * lda + k] : 0.f;
                    }
                    val.x = f2b(t[0]); val.y = f2b(t[1]); val.z = f2b(t[2]); val.w = f2b(t[3]);
                }
            } else if (AMODE == 1) {
                const unsigned short* A = (const unsigned short*)Aptr;
                if (full) {
                    val = *(const ushort4*)(A + (size_t)gm * lda + k0 + cc);
                } else {
                    unsigned short t[4];
#pragma unroll
                    for (int j = 0; j < 4; j++) {
                        int k = k0 + cc + j;
                        t[j] = (k < kend) ? A[(size_t)gm * lda + k] : (unsigned short)0;
                    }
                    val.x = t[0]; val.y = t[1]; val.z = t[2]; val.w = t[3];
                }
            } else {
                const float* se = (const float*)Aptr;
                int kc = k0 + cc;
                if (full && kc + 3 < 5705) {
                    const float* sp = se + (size_t)gm * 5705 + kc;
                    val.x = f2b(sp[0]); val.y = f2b(sp[1]);
                    val.z = f2b(sp[2]); val.w = f2b(sp[3]);
                } else {
                    float t[4];
#pragma unroll
                    for (int j = 0; j < 4; j++) {
                        int k = kc + j;
                        float v = 0.f;
                        if (k < kend) {
                            v = (k < 5705) ? se[(size_t)gm * 5705 + k]
                                           : A2ptr[(size_t)gm * 64 + (k - 5705)];
                        }
                        t[j] = v;
                    }
                    val.x = f2b(t[0]); val.y = f2b(t[1]); val.z = f2b(t[2]); val.w = f2b(t[3]);
                }
            }
            pa[i] = val;
        }
    };
    auto loadB = [&](int k0) {
        const bool full = (kend - k0) >= 32;
#pragma unroll
        for (int i = 0; i < NB; i++) {
            int f = tid + i * THREADS;
            int r = f >> 3, cc = (f & 7) * 4;
            int gn = n0 + r;
            ushort4 val;
            if (gn < N) {
                if (full) {
                    val = *(const ushort4*)(WT + (size_t)gn * ldwt + k0 + cc);
                } else {
                    unsigned short t[4];
#pragma unroll
                    for (int j = 0; j < 4; j++) {
                        int k = k0 + cc + j;
                        t[j] = (k < kend) ? WT[(size_t)gn * ldwt + k] : (unsigned short)0;
                    }
                    val.x = t[0]; val.y = t[1]; val.z = t[2]; val.w = t[3];
                }
            } else {
                val.x = val.y = val.z = val.w = 0;
            }
            pb[i] = val;
        }
    };

    loadA(kbeg);
    loadB(kbeg);

    for (int k0 = kbeg; k0 < kend; k0 += 32) {
        // ---- commit prefetched tiles to LDS ----
#pragma unroll
        for (int i = 0; i < NA; i++) {
            int f = tid + i * THREADS;
            int r = f >> 3, cc = (f & 7) * 4;
            *(ushort4*)&As[r * 40 + cc] = pa[i];
        }
#pragma unroll
        for (int i = 0; i < NB; i++) {
            int f = tid + i * THREADS;
            int r = f >> 3, cc = (f & 7) * 4;
            *(ushort4*)&Bs[r * 40 + cc] = pb[i];
        }
        __syncthreads();
        // ---- issue next iteration's global loads (overlap with MFMA) ----
        if (k0 + 32 < kend) {
            loadA(k0 + 32);
            loadB(k0 + 32);
        }
        // ---- compute: 16 MFMA ----
        s8 a[4], b[4];
#pragma unroll
        for (int mi = 0; mi < 4; mi++)
            a[mi] = *(const s8*)&As[(wm * 64 + mi * 16 + l16) * 40 + quad * 8];
#pragma unroll
        for (int ni = 0; ni < 4; ni++)
            b[ni] = *(const s8*)&Bs[(wn * 64 + ni * 16 + l16) * 40 + quad * 8];
#pragma unroll
        for (int mi = 0; mi < 4; mi++)
#pragma unroll
            for (int ni = 0; ni < 4; ni++)
                acc[mi][ni] = __builtin_amdgcn_mfma_f32_16x16x32_bf16(
                    a[mi], b[ni], acc[mi][ni], 0, 0, 0);
        __syncthreads();
    }

    // ---- epilogue: D[row=quad*4+r][col=l16] per frag ----
#pragma unroll
    for (int mi = 0; mi < 4; mi++) {
        int gmb = m0 + wm * 64 + mi * 16 + quad * 4;
#pragma unroll
        for (int ni = 0; ni < 4; ni++) {
            int gn = n0 + wn * 64 + ni * 16 + l16;
            if (gn < N) {
#pragma unroll
                for (int r = 0; r < 4; r++) {
                    float v = acc[mi][ni][r];
                    size_t off = (size_t)(gmb + r) * ldc + gn;
                    if (ATOMIC) {
                        atomicAdd((float*)Cptr + off, v);
                    } else {
                        if (bias) v += bias[gn];
                        if (ACT == 1) v = softplus_f(v);
                        if (OBF16) ((unsigned short*)Cptr)[off] = f2b(v);
                        else ((float*)Cptr)[off] = v;
                    }
                }
            }
        }
    }
}

// ---------------------------------------------------------------------------
// g-net: out[b,62+d] = sigmoid( sum_h sp(x*gW1[d,h]+gb1[d,h]) * gW2[d,h] + gb2[d] )
// ---------------------------------------------------------------------------
__global__ __launch_bounds__(256) void g_kernel(
    const float* __restrict__ flat,
    const float* __restrict__ gW1, const float* __restrict__ gb1,
    const float* __restrict__ gW2, const float* __restrict__ gb2,
    float* __restrict__ out) {
    __shared__ float w1[227], b1[227], w2[227];
    const int d = blockIdx.x;
    const int t = threadIdx.x;
    const int b = blockIdx.y * 256 + t;
    if (t < 227) {
        w1[t] = gW1[(size_t)d * 227 + t];
        b1[t] = gb1[(size_t)d * 227 + t];
        w2[t] = gW2[(size_t)d * 227 + t];
    }
    __syncthreads();
    float x = flat[(size_t)b * 228 + d];
    float acc = gb2[d];
    for (int h = 0; h < 227; h++) {
        float z = fmaf(x, w1[h], b1[h]);
        acc = fmaf(softplus_f(z), w2[h], acc);
    }
    out[(size_t)b * 415 + 62 + d] = sigmoid_f(acc);
}

// ---------------------------------------------------------------------------
__device__ __forceinline__ float lse12(const float* s) {
    float m = s[0];
#pragma unroll
    for (int j = 1; j < 12; j++) m = fmaxf(m, s[j]);
    float sum = 0.f;
#pragma unroll
    for (int j = 0; j < 12; j++) sum += __expf(s[j] - m);
    return m + __logf(sum);
}

__global__ __launch_bounds__(256) void heads_k(
    const float* __restrict__ flat, const float* __restrict__ ctx,
    const float* __restrict__ Wl, const float* __restrict__ Wsh, const float* __restrict__ Wm,
    const float* __restrict__ cWl, const float* __restrict__ cWsh, const float* __restrict__ cWm,
    float* __restrict__ out) {
    __shared__ float fl[227];
    __shared__ float cx[64];
    __shared__ float sraw[12], craw[12];
    __shared__ float lsf, lsc;
    const int b = blockIdx.x;
    const int t = threadIdx.x;
    if (t < 227) fl[t] = flat[(size_t)b * 228 + t];
    if (t < 64) cx[t] = ctx[(size_t)b * 64 + t];
    __syncthreads();
    float* ob = out + (size_t)b * 415;

    if (t < 25) {
        float a = 0.f;
        for (int k = 0; k < 227; k++) a = fmaf(fl[k], Wl[(size_t)k * 25 + t], a);
        ob[t] = a;
    } else if (t < 37) {
        int j = t - 25;
        float a = 0.f;
        for (int k = 0; k < 227; k++) a = fmaf(fl[k], Wsh[(size_t)k * 12 + j], a);
        sraw[j] = a;
    } else if (t < 62) {
        int j = t - 37;
        float a = 0.f;
        for (int k = 0; k < 227; k++) a = fmaf(fl[k], Wm[(size_t)k * 25 + j], a);
        ob[37 + j] = a;
    } else if (t >= 64 && t < 126) {
        int j2 = t - 64;
        if (j2 < 25) {
            float a = 0.f;
            for (int k = 0; k < 64; k++) a = fmaf(cx[k], cWl[(size_t)k * 25 + j2], a);
            ob[289 + j2] = a;
        } else if (j2 < 37) {
            int j = j2 - 25;
            float a = 0.f;
            for (int k = 0; k < 64; k++) a = fmaf(cx[k], cWsh[(size_t)k * 12 + j], a);
            craw[j] = a;
        } else {
            int j = j2 - 37;
            float a = 0.f;
            for (int k = 0; k < 64; k++) a = fmaf(cx[k], cWm[(size_t)k * 25 + j], a);
            ob[326 + j] = a;
        }
    } else if (t >= 128 && t < 192) {
        ob[351 + (t - 128)] = cx[t - 128];
    }
    __syncthreads();
    if (t == 0) lsf = lse12(sraw);
    if (t == 64) lsc = lse12(craw);
    __syncthreads();
    if (t < 12) ob[25 + t] = sraw[t] - lsf;
    else if (t >= 64 && t < 76) ob[314 + (t - 64)] = craw[t - 64] - lsc;
}

// ---------------------------------------------------------------------------
extern "C" void kernel_launch(void* const* d_in, const int* in_sizes, int n_in,
                              void* d_out, int out_size, void* d_ws, size_t ws_size,
                              hipStream_t stream) {
    const float* se    = (const float*)d_in[0];   // [4096,5705]
    const float* pz    = (const float*)d_in[1];   // [4096,64]
    const float* Wref  = (const float*)d_in[2];   // [7945,227]
    const float* fW1   = (const float*)d_in[3];
    const float* fb1   = (const float*)d_in[4];
    const float* fW2   = (const float*)d_in[5];
    const float* fb2   = (const float*)d_in[6];
    const float* fW3   = (const float*)d_in[7];
    const float* fb3   = (const float*)d_in[8];
    const float* gW1   = (const float*)d_in[9];
    const float* gb1   = (const float*)d_in[10];
    const float* gW2   = (const float*)d_in[11];
    const float* gb2   = (const float*)d_in[12];
    const float* Wland = (const float*)d_in[13];
    const float* Wshot = (const float*)d_in[14];
    const float* Wmove = (const float*)d_in[15];
    const float* cW1   = (const float*)d_in[16];
    const float* cb1   = (const float*)d_in[17];
    const float* cW2   = (const float*)d_in[18];
    const float* cb2   = (const float*)d_in[19];
    const float* cW3   = (const float*)d_in[20];
    const float* cb3   = (const float*)d_in[21];
    const float* cWl   = (const float*)d_in[22];
    const float* cWs   = (const float*)d_in[23];
    const float* cWm   = (const float*)d_in[24];
    float* out = (float*)d_out;
    const int M = 4096;

    // ---- workspace layout (~31.8 MB) ----
    char* p = (char*)d_ws;
    auto alloc = [&](size_t bytes) {
        char* r = p;
        p += (bytes + 255) & ~(size_t)255;
        return r;
    };
    unsigned short* WcatT = (unsigned short*)alloc((size_t)227 * 5776 * 2);
    unsigned short* cW1T  = (unsigned short*)alloc((size_t)1024 * 64 * 2);
    unsigned short* cW2T  = (unsigned short*)alloc((size_t)1024 * 1024 * 2);
    unsigned short* cW3T  = (unsigned short*)alloc((size_t)64 * 1024 * 2);
    unsigned short* fW1T  = (unsigned short*)alloc((size_t)1024 * 228 * 2);
    unsigned short* fW2T  = (unsigned short*)alloc((size_t)1024 * 1024 * 2);
    unsigned short* fW3T  = (unsigned short*)alloc((size_t)227 * 1024 * 2);
    unsigned short* h1    = (unsigned short*)alloc((size_t)M * 1024 * 2);
    unsigned short* h2    = (unsigned short*)alloc((size_t)M * 1024 * 2);
    float* fin  = (float*)alloc((size_t)M * 228 * 4);
    float* flat = (float*)alloc((size_t)M * 228 * 4);
    float* ctxb = (float*)alloc((size_t)M * 64 * 4);

    const dim3 tb(32, 8);
    // ---- weight prep (transpose + bf16) ----
    transpose_w<<<dim3(32, 2),  tb, 0, stream>>>(cW1, cW1T, 64, 1024, 64);
    transpose_w<<<dim3(32, 32), tb, 0, stream>>>(cW2, cW2T, 1024, 1024, 1024);
    transpose_w<<<dim3(2, 32),  tb, 0, stream>>>(cW3, cW3T, 1024, 64, 1024);
    transpose_w<<<dim3(32, 8),  tb, 0, stream>>>(fW1, fW1T, 227, 1024, 228);
    transpose_w<<<dim3(32, 32), tb, 0, stream>>>(fW2, fW2T, 1024, 1024, 1024);
    transpose_w<<<dim3(8, 32),  tb, 0, stream>>>(fW3, fW3T, 1024, 227, 1024);
    wcat_t<<<dim3(8, 181), tb, 0, stream>>>(Wref, WcatT);
    prefill_k<<<dim3((4096 * 228 + 4096 * 64 + 255) / 256), 256, 0, stream>>>(
        fin, flat, ctxb, fb3, cb3);

    // ---- context chain (BM=128, r4 grids, now pipelined) ----
    gemm_mfma<0, 1, false, true, 128><<<dim3(8, 32, 1), 256, 0, stream>>>(
        pz, 64, nullptr, cW1T, 64, cb1, h1, 1024, M, 1024, 64, 64);
    gemm_mfma<1, 1, false, true, 128><<<dim3(8, 32, 1), 256, 0, stream>>>(
        h1, 1024, nullptr, cW2T, 1024, cb2, h2, 1024, M, 1024, 1024, 1024);
    gemm_mfma<1, 0, true, false, 128><<<dim3(1, 32, 8), 256, 0, stream>>>(
        h2, 1024, nullptr, cW3T, 1024, nullptr, ctxb, 64, M, 64, 1024, 128);

    // ---- encoder: fin = [se|pz] @ Wcat (split-K=8, atomic f32) ----
    gemm_mfma<2, 0, true, false, 128><<<dim3(2, 32, 8), 256, 0, stream>>>(
        se, 5705, pz, WcatT, 5776, nullptr, fin, 228, M, 227, 5769, 736);

    // ---- f-decoder chain ----
    gemm_mfma<0, 1, false, true, 128><<<dim3(8, 32, 1), 256, 0, stream>>>(
        fin, 228, nullptr, fW1T, 228, fb1, h1, 1024, M, 1024, 227, 227);
    gemm_mfma<1, 1, false, true, 128><<<dim3(8, 32, 1), 256, 0, stream>>>(
        h1, 1024, nullptr, fW2T, 1024, fb2, h2, 1024, M, 1024, 1024, 1024);
    gemm_mfma<1, 0, true, false, 128><<<dim3(2, 32, 8), 256, 0, stream>>>(
        h2, 1024, nullptr, fW3T, 1024, nullptr, flat, 228, M, 227, 1024, 128);

    // ---- g-net + heads ----
    g_kernel<<<dim3(227, 16), 256, 0, stream>>>(flat, gW1, gb1, gW2, gb2, out);
    heads_k<<<dim3(4096), 256, 0, stream>>>(flat, ctxb, Wland, Wshot, Wmove,
                                            cWl, cWs, cWm, out);
}

// Round 9
// 815.181 us; speedup vs baseline: 1.1813x; 1.0842x over previous
//
#include <hip/hip_runtime.h>
#include <hip/hip_bf16.h>

using s8 = __attribute__((ext_vector_type(8))) short;
using f4 = __attribute__((ext_vector_type(4))) float;

__device__ __forceinline__ void glds16(const void* g, void* l) {
    __builtin_amdgcn_global_load_lds(
        (const __attribute__((address_space(1))) void*)g,
        (__attribute__((address_space(3))) void*)l, 16, 0, 0);
}

__device__ __forceinline__ unsigned short f2b(float f) {
    union { float f; unsigned u; } v; v.f = f;
    unsigned r = v.u + 0x7fffu + ((v.u >> 16) & 1u);
    return (unsigned short)(r >> 16);
}
__device__ __forceinline__ float softplus_f(float x) {
    return fmaxf(x, 0.f) + __logf(1.f + __expf(-fabsf(x)));
}
__device__ __forceinline__ float sigmoid_f(float x) {
    return 1.f / (1.f + __expf(-x));
}

// ---------------------------------------------------------------------------
// transpose + f32->bf16 with zero padding: dst[Npad][Kpad], dst[n][k]=src[k][n]
// grid (Npad/32, Kpad/32), block (32,8)
// ---------------------------------------------------------------------------
__global__ __launch_bounds__(256) void transpose_w(const float* __restrict__ src,
                                                   unsigned short* __restrict__ dst,
                                                   int K, int N, int Kpad, int Npad) {
    __shared__ float tile[32][33];
    const int n0 = blockIdx.x * 32, k0 = blockIdx.y * 32;
    const int tx = threadIdx.x, ty = threadIdx.y;
#pragma unroll
    for (int r = 0; r < 4; r++) {
        int k = k0 + ty + r * 8, n = n0 + tx;
        tile[ty + r * 8][tx] = (k < K && n < N) ? src[(size_t)k * N + n] : 0.f;
    }
    __syncthreads();
#pragma unroll
    for (int r = 0; r < 4; r++) {
        int n = n0 + ty + r * 8, k = k0 + tx;
        if (n < Npad && k < Kpad) dst[(size_t)n * Kpad + k] = f2b(tile[tx][ty + r * 8]);
    }
}

// ---------------------------------------------------------------------------
// WcatT[256][5792] bf16: n<227,k<5705 -> Wref[k+64*(k/163)][n];
//   5705<=k<5769 -> sum_t Wref[t*227+163+(k-5705)][n]; else 0.
// grid (8, 181), block (32,8)
// ---------------------------------------------------------------------------
__global__ __launch_bounds__(256) void wcat_t(const float* __restrict__ Wref,
                                              unsigned short* __restrict__ dst) {
    __shared__ float tile[32][33];
    const int n0 = blockIdx.x * 32, k0 = blockIdx.y * 32;
    const int tx = threadIdx.x, ty = threadIdx.y;
#pragma unroll
    for (int r = 0; r < 4; r++) {
        int k = k0 + ty + r * 8, n = n0 + tx;
        float v = 0.f;
        if (n < 227 && k < 5769) {
            if (k < 5705) {
                int wrow = k + 64 * (k / 163);
                v = Wref[(size_t)wrow * 227 + n];
            } else {
                int j2 = k - 5705;
                for (int t = 0; t < 35; t++)
                    v += Wref[(size_t)(t * 227 + 163 + j2) * 227 + n];
            }
        }
        tile[ty + r * 8][tx] = v;
    }
    __syncthreads();
#pragma unroll
    for (int r = 0; r < 4; r++) {
        int n = n0 + ty + r * 8, k = k0 + tx;
        if (n < 256 && k < 5792) dst[(size_t)n * 5792 + k] = f2b(tile[tx][ty + r * 8]);
    }
}

// ---------------------------------------------------------------------------
// Acat[4096][5792] bf16 = [bf16(se) | bf16(pz) | 0]. grid (23, 4096)
// ---------------------------------------------------------------------------
__global__ __launch_bounds__(256) void acat_k(const float* __restrict__ se,
                                              const float* __restrict__ pz,
                                              unsigned short* __restrict__ dst) {
    const int row = blockIdx.y;
    const int col = blockIdx.x * 256 + threadIdx.x;
    if (col >= 5792) return;
    float v = 0.f;
    if (col < 5705) v = se[(size_t)row * 5705 + col];
    else if (col < 5769) v = pz[(size_t)row * 64 + (col - 5705)];
    dst[(size_t)row * 5792 + col] = f2b(v);
}

__global__ __launch_bounds__(256) void cvt_k(const float* __restrict__ in,
                                             unsigned short* __restrict__ out, int n) {
    int i = blockIdx.x * 256 + threadIdx.x;
    if (i < n) out[i] = f2b(in[i]);
}

// finb[4096][256] bf16: col<227 -> bf16(fin[row*228+col]) else 0. grid (1,4096)
__global__ __launch_bounds__(256) void finb_k(const float* __restrict__ fin,
                                              unsigned short* __restrict__ out) {
    const int row = blockIdx.y, col = threadIdx.x;
    out[(size_t)row * 256 + col] = (col < 227) ? f2b(fin[(size_t)row * 228 + col])
                                               : (unsigned short)0;
}

// buf[row*ld+col] = (bias && col<ncr) ? bias[col] : 0
__global__ __launch_bounds__(256) void fillb_k(float* __restrict__ buf,
                                               const float* __restrict__ bias,
                                               int ld, int ncr) {
    const int row = blockIdx.y;
    const int col = blockIdx.x * 256 + threadIdx.x;
    if (col >= ld) return;
    float v = 0.f;
    if (bias && col < ncr) v = bias[col];
    buf[(size_t)row * ld + col] = v;
}

// out[i] = bf16(softplus(in[i])), 4/thread
__global__ __launch_bounds__(256) void sp_cvt_k(const float* __restrict__ in,
                                                unsigned short* __restrict__ out, int n) {
    int i = (blockIdx.x * 256 + threadIdx.x) * 4;
    if (i + 3 < n) {
        float4 v = *(const float4*)(in + i);
        ushort4 o;
        o.x = f2b(softplus_f(v.x)); o.y = f2b(softplus_f(v.y));
        o.z = f2b(softplus_f(v.z)); o.w = f2b(softplus_f(v.w));
        *(ushort4*)(out + i) = o;
    }
}

// ---------------------------------------------------------------------------
// m97-style DMA GEMM: C[4096,N] (+)= act(A @ WT^T + bias)
// A bf16 [4096][lda], WT bf16 [Npad][ldwt]; K,kchunk multiples of 32, buffers
// zero-padded so no tails. 128x128 tile, BK=32, 4 waves, 16x16x32_bf16.
// Staging via global_load_lds width=16 (async DMA, no VGPR round trip).
// ---------------------------------------------------------------------------
template <bool ATOMIC, int ACT, bool OBF16>
__global__ __launch_bounds__(256) void gemm_dma(
    const unsigned short* __restrict__ A, int lda,
    const unsigned short* __restrict__ WT, int ldwt,
    const float* __restrict__ bias,
    void* __restrict__ Cptr, int ldc, int N, int K, int kchunk) {
    __shared__ __align__(16) unsigned short As[128 * 32];
    __shared__ __align__(16) unsigned short Bs[128 * 32];
    const int tid = threadIdx.x;
    const int m0 = blockIdx.y * 128, n0 = blockIdx.x * 128;
    const int kbeg = blockIdx.z * kchunk;
    const int kend = min(kbeg + kchunk, K);
    const int lane = tid & 63, w = tid >> 6;
    const int wm = w >> 1, wn = w & 1;
    const int quad = lane >> 4, l16 = lane & 15;
    const int dr = lane >> 2;          // row within 16-row DMA chunk
    const int dk = (lane & 3) * 8;     // k offset (ushorts)

    f4 acc[4][4] = {};

    for (int k0 = kbeg; k0 < kend; k0 += 32) {
        // ---- async DMA staging: per wave 2x16 rows of A and of B ----
#pragma unroll
        for (int c = 0; c < 2; c++) {
            int rr = w * 32 + c * 16;
            glds16(A + (size_t)(m0 + rr + dr) * lda + k0 + dk, &As[rr * 32]);
            glds16(WT + (size_t)(n0 + rr + dr) * ldwt + k0 + dk, &Bs[rr * 32]);
        }
        __syncthreads();  // compiler drains vmcnt before barrier -> tiles ready
        s8 a[4], b[4];
#pragma unroll
        for (int mi = 0; mi < 4; mi++)
            a[mi] = *(const s8*)&As[(wm * 64 + mi * 16 + l16) * 32 + quad * 8];
#pragma unroll
        for (int ni = 0; ni < 4; ni++)
            b[ni] = *(const s8*)&Bs[(wn * 64 + ni * 16 + l16) * 32 + quad * 8];
#pragma unroll
        for (int mi = 0; mi < 4; mi++)
#pragma unroll
            for (int ni = 0; ni < 4; ni++)
                acc[mi][ni] = __builtin_amdgcn_mfma_f32_16x16x32_bf16(
                    a[mi], b[ni], acc[mi][ni], 0, 0, 0);
        __syncthreads();
    }

#pragma unroll
    for (int mi = 0; mi < 4; mi++) {
        int gmb = m0 + wm * 64 + mi * 16 + quad * 4;
#pragma unroll
        for (int ni = 0; ni < 4; ni++) {
            int gn = n0 + wn * 64 + ni * 16 + l16;
            if (gn < N) {
#pragma unroll
                for (int r = 0; r < 4; r++) {
                    float v = acc[mi][ni][r];
                    size_t off = (size_t)(gmb + r) * ldc + gn;
                    if (ATOMIC) {
                        atomicAdd((float*)Cptr + off, v);
                    } else {
                        if (bias) v += bias[gn];
                        if (ACT == 1) v = softplus_f(v);
                        if (OBF16) ((unsigned short*)Cptr)[off] = f2b(v);
                        else ((float*)Cptr)[off] = v;
                    }
                }
            }
        }
    }
}

// ---------------------------------------------------------------------------
// FALLBACK (r6 known-good): VGPR-staged GEMM with register prefetch.
// ---------------------------------------------------------------------------
template <int AMODE, int ACT, bool ATOMIC, bool OBF16>
__global__ __launch_bounds__(256) void gemm_mfma(
    const void* __restrict__ Aptr, int lda,
    const float* __restrict__ A2ptr,
    const unsigned short* __restrict__ WT, int ldwt,
    const float* __restrict__ bias,
    void* __restrict__ Cptr, int ldc,
    int M, int N, int K, int kchunk) {
    __shared__ unsigned short As[128 * 40];
    __shared__ unsigned short Bs[128 * 40];
    const int tid = threadIdx.x;
    const int m0 = blockIdx.y * 128, n0 = blockIdx.x * 128;
    const int kbeg = blockIdx.z * kchunk;
    const int kend = min(kbeg + kchunk, K);
    const int lane = tid & 63, w = tid >> 6;
    const int wm = w >> 1, wn = w & 1;
    const int quad = lane >> 4, l16 = lane & 15;

    f4 acc[4][4] = {};
    ushort4 pa[4], pb[4];

    auto loadA = [&](int k0) {
        const bool full = (kend - k0) >= 32;
#pragma unroll
        for (int i = 0; i < 4; i++) {
            int f = tid + i * 256;
            int r = f >> 3, cc = (f & 7) * 4;
            int gm = m0 + r;
            ushort4 val;
            if (AMODE == 0) {
                const float* A = (const float*)Aptr;
                float t[4];
#pragma unroll
                for (int j = 0; j < 4; j++) {
                    int k = k0 + cc + j;
                    t[j] = (k < kend) ? A[(size_t)gm * lda + k] : 0.f;
                }
                val.x = f2b(t[0]); val.y = f2b(t[1]); val.z = f2b(t[2]); val.w = f2b(t[3]);
            } else if (AMODE == 1) {
                const unsigned short* A = (const unsigned short*)Aptr;
                if (full) {
                    val = *(const ushort4*)(A + (size_t)gm * lda + k0 + cc);
                } else {
                    unsigned short t[4];
#pragma unroll
                    for (int j = 0; j < 4; j++) {
                        int k = k0 + cc + j;
                        t[j] = (k < kend) ? A[(size_t)gm * lda + k] : (unsigned short)0;
                    }
                    val.x = t[0]; val.y = t[1]; val.z = t[2]; val.w = t[3];
                }
            } else {
                const float* se = (const float*)Aptr;
                float t[4];
#pragma unroll
                for (int j = 0; j < 4; j++) {
                    int k = k0 + cc + j;
                    float v = 0.f;
                    if (k < kend) {
                        v = (k < 5705) ? se[(size_t)gm * 5705 + k]
                                       : A2ptr[(size_t)gm * 64 + (k - 5705)];
                    }
                    t[j] = v;
                }
                val.x = f2b(t[0]); val.y = f2b(t[1]); val.z = f2b(t[2]); val.w = f2b(t[3]);
            }
            pa[i] = val;
        }
    };
    auto loadB = [&](int k0) {
        const bool full = (kend - k0) >= 32;
#pragma unroll
        for (int i = 0; i < 4; i++) {
            int f = tid + i * 256;
            int r = f >> 3, cc = (f & 7) * 4;
            int gn = n0 + r;
            ushort4 val;
            if (gn < N) {
                if (full) {
                    val = *(const ushort4*)(WT + (size_t)gn * ldwt + k0 + cc);
                } else {
                    unsigned short t[4];
#pragma unroll
                    for (int j = 0; j < 4; j++) {
                        int k = k0 + cc + j;
                        t[j] = (k < kend) ? WT[(size_t)gn * ldwt + k] : (unsigned short)0;
                    }
                    val.x = t[0]; val.y = t[1]; val.z = t[2]; val.w = t[3];
                }
            } else {
                val.x = val.y = val.z = val.w = 0;
            }
            pb[i] = val;
        }
    };

    loadA(kbeg); loadB(kbeg);
    for (int k0 = kbeg; k0 < kend; k0 += 32) {
#pragma unroll
        for (int i = 0; i < 4; i++) {
            int f = tid + i * 256;
            int r = f >> 3, cc = (f & 7) * 4;
            *(ushort4*)&As[r * 40 + cc] = pa[i];
        }
#pragma unroll
        for (int i = 0; i < 4; i++) {
            int f = tid + i * 256;
            int r = f >> 3, cc = (f & 7) * 4;
            *(ushort4*)&Bs[r * 40 + cc] = pb[i];
        }
        __syncthreads();
        if (k0 + 32 < kend) { loadA(k0 + 32); loadB(k0 + 32); }
        s8 a[4], b[4];
#pragma unroll
        for (int mi = 0; mi < 4; mi++)
            a[mi] = *(const s8*)&As[(wm * 64 + mi * 16 + l16) * 40 + quad * 8];
#pragma unroll
        for (int ni = 0; ni < 4; ni++)
            b[ni] = *(const s8*)&Bs[(wn * 64 + ni * 16 + l16) * 40 + quad * 8];
#pragma unroll
        for (int mi = 0; mi < 4; mi++)
#pragma unroll
            for (int ni = 0; ni < 4; ni++)
                acc[mi][ni] = __builtin_amdgcn_mfma_f32_16x16x32_bf16(
                    a[mi], b[ni], acc[mi][ni], 0, 0, 0);
        __syncthreads();
    }
#pragma unroll
    for (int mi = 0; mi < 4; mi++) {
        int gmb = m0 + wm * 64 + mi * 16 + quad * 4;
#pragma unroll
        for (int ni = 0; ni < 4; ni++) {
            int gn = n0 + wn * 64 + ni * 16 + l16;
            if (gn < N) {
#pragma unroll
                for (int r = 0; r < 4; r++) {
                    float v = acc[mi][ni][r];
                    size_t off = (size_t)(gmb + r) * ldc + gn;
                    if (ATOMIC) {
                        atomicAdd((float*)Cptr + off, v);
                    } else {
                        if (bias) v += bias[gn];
                        if (ACT == 1) v = softplus_f(v);
                        if (OBF16) ((unsigned short*)Cptr)[off] = f2b(v);
                        else ((float*)Cptr)[off] = v;
                    }
                }
            }
        }
    }
}

// ---------------------------------------------------------------------------
__global__ __launch_bounds__(256) void g_kernel(
    const float* __restrict__ flat,
    const float* __restrict__ gW1, const float* __restrict__ gb1,
    const float* __restrict__ gW2, const float* __restrict__ gb2,
    float* __restrict__ out) {
    __shared__ float w1[227], b1[227], w2[227];
    const int d = blockIdx.x;
    const int t = threadIdx.x;
    const int b = blockIdx.y * 256 + t;
    if (t < 227) {
        w1[t] = gW1[(size_t)d * 227 + t];
        b1[t] = gb1[(size_t)d * 227 + t];
        w2[t] = gW2[(size_t)d * 227 + t];
    }
    __syncthreads();
    float x = flat[(size_t)b * 228 + d];
    float acc = gb2[d];
    for (int h = 0; h < 227; h++) {
        float z = fmaf(x, w1[h], b1[h]);
        acc = fmaf(softplus_f(z), w2[h], acc);
    }
    out[(size_t)b * 415 + 62 + d] = sigmoid_f(acc);
}

__device__ __forceinline__ float lse12(const float* s) {
    float m = s[0];
#pragma unroll
    for (int j = 1; j < 12; j++) m = fmaxf(m, s[j]);
    float sum = 0.f;
#pragma unroll
    for (int j = 0; j < 12; j++) sum += __expf(s[j] - m);
    return m + __logf(sum);
}

__global__ __launch_bounds__(256) void heads_k(
    const float* __restrict__ flat, const float* __restrict__ ctx,
    const float* __restrict__ Wl, const float* __restrict__ Wsh, const float* __restrict__ Wm,
    const float* __restrict__ cWl, const float* __restrict__ cWsh, const float* __restrict__ cWm,
    float* __restrict__ out) {
    __shared__ float fl[227];
    __shared__ float cx[64];
    __shared__ float sraw[12], craw[12];
    __shared__ float lsf, lsc;
    const int b = blockIdx.x;
    const int t = threadIdx.x;
    if (t < 227) fl[t] = flat[(size_t)b * 228 + t];
    if (t < 64) cx[t] = ctx[(size_t)b * 64 + t];
    __syncthreads();
    float* ob = out + (size_t)b * 415;

    if (t < 25) {
        float a = 0.f;
        for (int k = 0; k < 227; k++) a = fmaf(fl[k], Wl[(size_t)k * 25 + t], a);
        ob[t] = a;
    } else if (t < 37) {
        int j = t - 25;
        float a = 0.f;
        for (int k = 0; k < 227; k++) a = fmaf(fl[k], Wsh[(size_t)k * 12 + j], a);
        sraw[j] = a;
    } else if (t < 62) {
        int j = t - 37;
        float a = 0.f;
        for (int k = 0; k < 227; k++) a = fmaf(fl[k], Wm[(size_t)k * 25 + j], a);
        ob[37 + j] = a;
    } else if (t >= 64 && t < 126) {
        int j2 = t - 64;
        if (j2 < 25) {
            float a = 0.f;
            for (int k = 0; k < 64; k++) a = fmaf(cx[k], cWl[(size_t)k * 25 + j2], a);
            ob[289 + j2] = a;
        } else if (j2 < 37) {
            int j = j2 - 25;
            float a = 0.f;
            for (int k = 0; k < 64; k++) a = fmaf(cx[k], cWsh[(size_t)k * 12 + j], a);
            craw[j] = a;
        } else {
            int j = j2 - 37;
            float a = 0.f;
            for (int k = 0; k < 64; k++) a = fmaf(cx[k], cWm[(size_t)k * 25 + j], a);
            ob[326 + j] = a;
        }
    } else if (t >= 128 && t < 192) {
        ob[351 + (t - 128)] = cx[t - 128];
    }
    __syncthreads();
    if (t == 0) lsf = lse12(sraw);
    if (t == 64) lsc = lse12(craw);
    __syncthreads();
    if (t < 12) ob[25 + t] = sraw[t] - lsf;
    else if (t >= 64 && t < 76) ob[314 + (t - 64)] = craw[t - 64] - lsc;
}

// ---------------------------------------------------------------------------
extern "C" void kernel_launch(void* const* d_in, const int* in_sizes, int n_in,
                              void* d_out, int out_size, void* d_ws, size_t ws_size,
                              hipStream_t stream) {
    const float* se    = (const float*)d_in[0];
    const float* pz    = (const float*)d_in[1];
    const float* Wref  = (const float*)d_in[2];
    const float* fW1   = (const float*)d_in[3];
    const float* fb1   = (const float*)d_in[4];
    const float* fW2   = (const float*)d_in[5];
    const float* fb2   = (const float*)d_in[6];
    const float* fW3   = (const float*)d_in[7];
    const float* fb3   = (const float*)d_in[8];
    const float* gW1   = (const float*)d_in[9];
    const float* gb1   = (const float*)d_in[10];
    const float* gW2   = (const float*)d_in[11];
    const float* gb2   = (const float*)d_in[12];
    const float* Wland = (const float*)d_in[13];
    const float* Wshot = (const float*)d_in[14];
    const float* Wmove = (const float*)d_in[15];
    const float* cW1   = (const float*)d_in[16];
    const float* cb1   = (const float*)d_in[17];
    const float* cW2   = (const float*)d_in[18];
    const float* cb2   = (const float*)d_in[19];
    const float* cW3   = (const float*)d_in[20];
    const float* cb3   = (const float*)d_in[21];
    const float* cWl   = (const float*)d_in[22];
    const float* cWs   = (const float*)d_in[23];
    const float* cWm   = (const float*)d_in[24];
    float* out = (float*)d_out;
    const int M = 4096;

    char* p = (char*)d_ws;
    auto alloc = [&](size_t bytes) {
        char* r = p;
        p += (bytes + 255) & ~(size_t)255;
        return r;
    };
    // ---- common base (~32.3 MB, known to fit: r3 used 34.66 MB) ----
    unsigned short* WcatT = (unsigned short*)alloc((size_t)256 * 5792 * 2);
    unsigned short* cW1T  = (unsigned short*)alloc((size_t)1024 * 64 * 2);
    unsigned short* cW2T  = (unsigned short*)alloc((size_t)1024 * 1024 * 2);
    unsigned short* cW3T  = (unsigned short*)alloc((size_t)128 * 1024 * 2);
    unsigned short* fW1T  = (unsigned short*)alloc((size_t)1024 * 256 * 2);
    unsigned short* fW2T  = (unsigned short*)alloc((size_t)1024 * 1024 * 2);
    unsigned short* fW3T  = (unsigned short*)alloc((size_t)256 * 1024 * 2);
    float* fin  = (float*)alloc((size_t)M * 228 * 4);
    float* flat = (float*)alloc((size_t)M * 228 * 4);
    float* ctxb = (float*)alloc((size_t)M * 64 * 4);
    unsigned short* h2b  = (unsigned short*)alloc((size_t)M * 1024 * 2);
    unsigned short* h1fb = (unsigned short*)alloc((size_t)M * 1024 * 2);

    size_t base_used = (size_t)(p - (char*)d_ws);
    size_t full_extra = (size_t)M * 64 * 2            // pzb
                      + (size_t)M * 256 * 2           // finb
                      + (size_t)M * 5792 * 2;         // region (Acat / h2f+h1b)
    const bool full = (base_used + full_extra + 65536) <= ws_size;

    const dim3 tb(32, 8);
    // ---- weight prep (transpose + bf16, zero-padded) ----
    transpose_w<<<dim3(32, 2),  tb, 0, stream>>>(cW1, cW1T, 64, 1024, 64, 1024);
    transpose_w<<<dim3(32, 32), tb, 0, stream>>>(cW2, cW2T, 1024, 1024, 1024, 1024);
    transpose_w<<<dim3(4, 32),  tb, 0, stream>>>(cW3, cW3T, 1024, 64, 1024, 128);
    transpose_w<<<dim3(32, 8),  tb, 0, stream>>>(fW1, fW1T, 227, 1024, 256, 1024);
    transpose_w<<<dim3(32, 32), tb, 0, stream>>>(fW2, fW2T, 1024, 1024, 1024, 1024);
    transpose_w<<<dim3(8, 32),  tb, 0, stream>>>(fW3, fW3T, 1024, 227, 1024, 256);
    wcat_t<<<dim3(8, 181), tb, 0, stream>>>(Wref, WcatT);
    // fills: fin=0, flat=fb3, ctxb=cb3 (split-K targets pre-biased)
    fillb_k<<<dim3(1, M), 256, 0, stream>>>(fin, nullptr, 228, 0);
    fillb_k<<<dim3(1, M), 256, 0, stream>>>(flat, fb3, 228, 227);
    fillb_k<<<dim3(1, M), 256, 0, stream>>>(ctxb, cb3, 64, 64);

    if (full) {
        unsigned short* pzb  = (unsigned short*)alloc((size_t)M * 64 * 2);
        unsigned short* finb = (unsigned short*)alloc((size_t)M * 256 * 2);
        char* region = alloc((size_t)M * 5792 * 2);
        unsigned short* Acat = (unsigned short*)region;
        float* h2f = (float*)region;                                    // 16.78 MB
        unsigned short* h1b = (unsigned short*)(region + (size_t)M * 1024 * 4);

        cvt_k<<<dim3((M * 64 + 255) / 256), 256, 0, stream>>>(pz, pzb, M * 64);
        acat_k<<<dim3(23, M), 256, 0, stream>>>(se, pz, Acat);

        // encoder: fin += Acat @ WcatT^T  (K=5792, z=12, 768 blocks)
        gemm_dma<true, 0, false><<<dim3(2, 32, 12), 256, 0, stream>>>(
            Acat, 5792, WcatT, 5792, nullptr, fin, 228, 227, 5792, 512);
        finb_k<<<dim3(1, M), 256, 0, stream>>>(fin, finb);
        // Acat dead; region now hosts h2f / h1b

        // c1: h1b = sp(pzb @ cW1T + cb1), direct
        gemm_dma<false, 1, true><<<dim3(8, 32, 1), 256, 0, stream>>>(
            pzb, 64, cW1T, 64, cb1, h1b, 1024, 1024, 64, 64);
        // c2: h2f = cb2 + h1b @ cW2T (z=3); h2b = sp(h2f)
        fillb_k<<<dim3(4, M), 256, 0, stream>>>(h2f, cb2, 1024, 1024);
        gemm_dma<true, 0, false><<<dim3(8, 32, 3), 256, 0, stream>>>(
            h1b, 1024, cW2T, 1024, nullptr, h2f, 1024, 1024, 1024, 352);
        sp_cvt_k<<<dim3(M), 256, 0, stream>>>(h2f, h2b, M * 1024);
        // c3: ctxb += h2b @ cW3T (z=16)
        gemm_dma<true, 0, false><<<dim3(1, 32, 16), 256, 0, stream>>>(
            h2b, 1024, cW3T, 1024, nullptr, ctxb, 64, 64, 1024, 64);

        // f1: h1b = sp(finb @ fW1T + fb1), direct (K=256)
        gemm_dma<false, 1, true><<<dim3(8, 32, 1), 256, 0, stream>>>(
            finb, 256, fW1T, 256, fb1, h1b, 1024, 1024, 256, 256);
        // f2: h2f = fb2 + h1b @ fW2T (z=3); h2b = sp(h2f)
        fillb_k<<<dim3(4, M), 256, 0, stream>>>(h2f, fb2, 1024, 1024);
        gemm_dma<true, 0, false><<<dim3(8, 32, 3), 256, 0, stream>>>(
            h1b, 1024, fW2T, 1024, nullptr, h2f, 1024, 1024, 1024, 352);
        sp_cvt_k<<<dim3(M), 256, 0, stream>>>(h2f, h2b, M * 1024);
        // f3: flat += h2b @ fW3T (z=8)
        gemm_dma<true, 0, false><<<dim3(2, 32, 8), 256, 0, stream>>>(
            h2b, 1024, fW3T, 1024, nullptr, flat, 228, 227, 1024, 128);
    } else {
        // -------- fallback: r6 structure (known-good 884 us) --------
        unsigned short* h1 = h1fb;
        gemm_mfma<0, 1, false, true><<<dim3(8, 32, 1), 256, 0, stream>>>(
            pz, 64, nullptr, cW1T, 64, cb1, h1, 1024, M, 1024, 64, 64);
        gemm_mfma<1, 1, false, true><<<dim3(8, 32, 1), 256, 0, stream>>>(
            h1, 1024, nullptr, cW2T, 1024, cb2, h2b, 1024, M, 1024, 1024, 1024);
        gemm_mfma<1, 0, true, false><<<dim3(1, 32, 8), 256, 0, stream>>>(
            h2b, 1024, nullptr, cW3T, 1024, nullptr, ctxb, 64, M, 64, 1024, 128);
        gemm_mfma<2, 0, true, false><<<dim3(2, 32, 8), 256, 0, stream>>>(
            se, 5705, pz, WcatT, 5792, nullptr, fin, 228, M, 227, 5769, 736);
        gemm_mfma<0, 1, false, true><<<dim3(8, 32, 1), 256, 0, stream>>>(
            fin, 228, nullptr, fW1T, 256, fb1, h1, 1024, M, 1024, 227, 227);
        gemm_mfma<1, 1, false, true><<<dim3(8, 32, 1), 256, 0, stream>>>(
            h1, 1024, nullptr, fW2T, 1024, fb2, h2b, 1024, M, 1024, 1024, 1024);
        gemm_mfma<1, 0, true, false><<<dim3(2, 32, 8), 256, 0, stream>>>(
            h2b, 1024, nullptr, fW3T, 1024, nullptr, flat, 228, M, 227, 1024, 128);
    }

    g_kernel<<<dim3(227, 16), 256, 0, stream>>>(flat, gW1, gb1, gW2, gb2, out);
    heads_k<<<dim3(4096), 256, 0, stream>>>(flat, ctxb, Wland, Wshot, Wmove,
                                            cWl, cWs, cWm, out);
}